// Round 3
// baseline (930.085 us; speedup 1.0000x reference)
//
#include <hip/hip_runtime.h>

#define DIM 64
#define NPB 256          // nodes per bucket (bucket id = dst >> 8)
#define MAXBUCK 512      // N up to 131072
#define CHUNK 4096       // edges per binning block

// h = x @ W   (x: [N,64], W: [64,64])
__global__ void gcn_matmul(const float* __restrict__ x, const float* __restrict__ W,
                           float* __restrict__ h, int N) {
    __shared__ float Wl[DIM][DIM];
    __shared__ float xs[4][DIM];
    int tid = threadIdx.x;
    for (int i = tid; i < DIM * DIM; i += 256) Wl[i / DIM][i % DIM] = W[i];
    int node0 = blockIdx.x * 4;
    int gidx = node0 * DIM + tid;
    xs[tid / DIM][tid % DIM] = (gidx < N * DIM) ? x[gidx] : 0.f;
    __syncthreads();
    int nl = tid / DIM, d = tid % DIM;
    int node = node0 + nl;
    if (node < N) {
        float acc = 0.f;
#pragma unroll
        for (int k = 0; k < DIM; ++k) acc += xs[nl][k] * Wl[k][d];
        h[node * DIM + d] = acc;
    }
}

__global__ void zero_i32(int* __restrict__ p, int n) {
    int i = blockIdx.x * 256 + threadIdx.x;
    if (i < n) p[i] = 0;
}

// per-node degree atomics + per-bucket histogram (LDS-aggregated)
__global__ void count_pass(const int* __restrict__ ei, int* __restrict__ cnt,
                           int* __restrict__ bcount, int E, int nbuck) {
    __shared__ int hist[MAXBUCK];
    int tid = threadIdx.x;
    for (int i = tid; i < nbuck; i += 256) hist[i] = 0;
    __syncthreads();
    for (int e = blockIdx.x * 256 + tid; e < E; e += gridDim.x * 256) {
        int t = ei[E + e];
        atomicAdd(&cnt[t], 1);
        atomicAdd(&hist[t >> 8], 1);
    }
    __syncthreads();
    for (int i = tid; i < nbuck; i += 256)
        if (hist[i]) atomicAdd(&bcount[i], hist[i]);
}

__global__ void calc_dinv(const int* __restrict__ cnt, float* __restrict__ dinv, int N) {
    int i = blockIdx.x * 256 + threadIdx.x;
    if (i < N) dinv[i] = rsqrtf((float)cnt[i] + 1.0f);
}

// single-block exclusive scan of bucket counts -> boff, init bcur
__global__ void scan_buckets(const int* __restrict__ bcount, int* __restrict__ boff,
                             int* __restrict__ bcur, int nbuck, int E) {
    __shared__ int sh[MAXBUCK];
    int tid = threadIdx.x;  // 512
    int v = (tid < nbuck) ? bcount[tid] : 0;
    sh[tid] = v;
    __syncthreads();
    for (int d = 1; d < MAXBUCK; d <<= 1) {
        int t = (tid >= d) ? sh[tid - d] : 0;
        __syncthreads();
        sh[tid] += t;
        __syncthreads();
    }
    if (tid < nbuck) {
        int o = sh[tid] - v;
        boff[tid] = o;
        bcur[tid] = o;
    }
    if (tid == 0) boff[nbuck] = E;
}

// bin edges into bucket-contiguous storage; packed entry = (src<<8) | (dst&255)
__global__ void bin_edges(const int* __restrict__ ei, int* __restrict__ bcur,
                          unsigned* __restrict__ binned, int E, int nbuck) {
    __shared__ int hist[MAXBUCK];
    int tid = threadIdx.x;
    long e0 = (long)blockIdx.x * CHUNK;
    for (int i = tid; i < nbuck; i += 256) hist[i] = 0;
    __syncthreads();
    int s[16], t[16];
#pragma unroll
    for (int it = 0; it < 16; ++it) {
        long e = e0 + it * 256 + tid;
        if (e < E) {
            s[it] = ei[e];
            t[it] = ei[E + e];
            atomicAdd(&hist[t[it] >> 8], 1);
        } else {
            s[it] = -1;
        }
    }
    __syncthreads();
    // reserve a contiguous global range per (block,bucket); hist becomes cursor
    for (int i = tid; i < nbuck; i += 256) {
        int c = hist[i];
        hist[i] = c ? atomicAdd(&bcur[i], c) : 0;
    }
    __syncthreads();
#pragma unroll
    for (int it = 0; it < 16; ++it) {
        if (s[it] >= 0) {
            int b = t[it] >> 8;
            int p = atomicAdd(&hist[b], 1);
            binned[p] = ((unsigned)s[it] << 8) | (unsigned)(t[it] & 255);
        }
    }
}

// one block per bucket: LDS-resident agg rows, LDS float atomics, fused epilogue
__global__ void __launch_bounds__(512, 2)
aggregate(const int* __restrict__ boff, const unsigned* __restrict__ binned,
          const float* __restrict__ h, const float* __restrict__ dinv,
          const float* __restrict__ x, const float* __restrict__ bias,
          float* __restrict__ out, int N) {
    __shared__ float agg[NPB][DIM];  // 64 KB
    int bid = blockIdx.x;
    int node0 = bid << 8;
    int tid = threadIdx.x;           // 512 = 8 waves
    int lane = tid & 63, wid = tid >> 6;
    for (int i = tid; i < NPB * DIM; i += 512) ((float*)agg)[i] = 0.f;
    __syncthreads();
    int e0 = boff[bid], e1 = boff[bid + 1];
    for (int c = e0 + wid * 64; c < e1; c += 8 * 64) {
        int take = e1 - c;
        if (take > 64) take = 64;
        unsigned v = (lane < take) ? binned[c + lane] : 0u;
        int s = v >> 8;
        int r = v & 255;
        float w = (lane < take) ? dinv[s] : 0.f;
        for (int i = 0; i < take; ++i) {
            int si = __shfl(s, i);
            int ri = __shfl(r, i);
            float wi = __shfl(w, i);
            atomicAdd(&agg[ri][lane], h[(long)si * DIM + lane] * wi);
        }
    }
    __syncthreads();
    for (int r = wid; r < NPB; r += 8) {
        int n = node0 + r;
        if (n >= N) continue;
        float dn = dinv[n];
        long gi = (long)n * DIM + lane;
        float val = (agg[r][lane] + h[gi] * dn) * dn + bias[lane];
        out[gi] = x[gi] + fmaxf(val, 0.f);
    }
}

extern "C" void kernel_launch(void* const* d_in, const int* in_sizes, int n_in,
                              void* d_out, int out_size, void* d_ws, size_t ws_size,
                              hipStream_t stream) {
    const float* x = (const float*)d_in[0];
    const int* ei  = (const int*)d_in[1];
    const float* W = (const float*)d_in[2];
    const float* b = (const float*)d_in[3];
    float* out = (float*)d_out;

    int N = in_sizes[0] / DIM;
    int E = in_sizes[1] / 2;
    int nbuck = (N + NPB - 1) / NPB;  // 391

    char* ws = (char*)d_ws;
    size_t o = 0;
    float* h     = (float*)(ws + o); o += (size_t)N * DIM * sizeof(float);
    int*   cnt   = (int*)(ws + o);   o += (size_t)N * sizeof(int);
    float* dinv  = (float*)(ws + o); o += (size_t)N * sizeof(float);
    int*   bcount= (int*)(ws + o);   o += (size_t)nbuck * sizeof(int);
    int*   boff  = (int*)(ws + o);   o += (size_t)(nbuck + 1) * sizeof(int);
    int*   bcur  = (int*)(ws + o);   o += (size_t)nbuck * sizeof(int);
    unsigned* binned = (unsigned*)(ws + o); o += (size_t)E * sizeof(unsigned);

    gcn_matmul<<<(N + 3) / 4, 256, 0, stream>>>(x, W, h, N);
    zero_i32<<<(N + 255) / 256, 256, 0, stream>>>(cnt, N);
    zero_i32<<<(nbuck + 255) / 256, 256, 0, stream>>>(bcount, nbuck);
    count_pass<<<512, 256, 0, stream>>>(ei, cnt, bcount, E, nbuck);
    calc_dinv<<<(N + 255) / 256, 256, 0, stream>>>(cnt, dinv, N);
    scan_buckets<<<1, MAXBUCK, 0, stream>>>(bcount, boff, bcur, nbuck, E);
    bin_edges<<<(int)((E + CHUNK - 1) / CHUNK), 256, 0, stream>>>(ei, bcur, binned, E, nbuck);
    aggregate<<<nbuck, 512, 0, stream>>>(boff, binned, h, dinv, x, b, out, N);
}

// Round 9
// 223.180 us; speedup vs baseline: 4.1674x; 4.1674x over previous
//
#include <hip/hip_runtime.h>

#define DIM 64
#define NPB 256          // nodes per bucket (bucket id = dst >> 8)
#define MAXBUCK 512      // N up to 131072
#define CHUNK 4096       // edges per binning block

// h = x @ W   (x: [N,64], W: [64,64])
__global__ void gcn_matmul(const float* __restrict__ x, const float* __restrict__ W,
                           float* __restrict__ h, int N) {
    __shared__ float Wl[DIM][DIM];
    __shared__ float xs[4][DIM];
    int tid = threadIdx.x;
    for (int i = tid; i < DIM * DIM; i += 256) Wl[i / DIM][i % DIM] = W[i];
    int node0 = blockIdx.x * 4;
    int gidx = node0 * DIM + tid;
    xs[tid / DIM][tid % DIM] = (gidx < N * DIM) ? x[gidx] : 0.f;
    __syncthreads();
    int nl = tid / DIM, d = tid % DIM;
    int node = node0 + nl;
    if (node < N) {
        float acc = 0.f;
#pragma unroll
        for (int k = 0; k < DIM; ++k) acc += xs[nl][k] * Wl[k][d];
        h[node * DIM + d] = acc;
    }
}

__global__ void zero_i32(int* __restrict__ p, int n) {
    int i = blockIdx.x * 256 + threadIdx.x;
    if (i < n) p[i] = 0;
}

// bucket histogram only (LDS-aggregated, no per-node atomics)
__global__ void count_buckets(const int* __restrict__ ei, int* __restrict__ bcount,
                              int E, int nbuck) {
    __shared__ int hist[MAXBUCK];
    int tid = threadIdx.x;
    for (int i = tid; i < nbuck; i += 256) hist[i] = 0;
    __syncthreads();
    for (long e = (long)blockIdx.x * 256 + tid; e < E; e += (long)gridDim.x * 256)
        atomicAdd(&hist[ei[E + e] >> 8], 1);
    __syncthreads();
    for (int i = tid; i < nbuck; i += 256)
        if (hist[i]) atomicAdd(&bcount[i], hist[i]);
}

// single-block exclusive scan of bucket counts -> boff, init bcur
__global__ void scan_buckets(const int* __restrict__ bcount, int* __restrict__ boff,
                             int* __restrict__ bcur, int nbuck, int E) {
    __shared__ int sh[MAXBUCK];
    int tid = threadIdx.x;  // 512
    int v = (tid < nbuck) ? bcount[tid] : 0;
    sh[tid] = v;
    __syncthreads();
    for (int d = 1; d < MAXBUCK; d <<= 1) {
        int t = (tid >= d) ? sh[tid - d] : 0;
        __syncthreads();
        sh[tid] += t;
        __syncthreads();
    }
    if (tid < nbuck) {
        int o = sh[tid] - v;
        boff[tid] = o;
        bcur[tid] = o;
    }
    if (tid == 0) boff[nbuck] = E;
}

// phase A: bin edges into bucket-contiguous storage; entry = (src<<8) | (dst&255)
__global__ void bin_edges(const int* __restrict__ ei, int* __restrict__ bcur,
                          unsigned* __restrict__ binned, int E, int nbuck) {
    __shared__ int hist[MAXBUCK];
    int tid = threadIdx.x;
    long e0 = (long)blockIdx.x * CHUNK;
    for (int i = tid; i < nbuck; i += 256) hist[i] = 0;
    __syncthreads();
    int s[16], t[16];
#pragma unroll
    for (int it = 0; it < 16; ++it) {
        long e = e0 + it * 256 + tid;
        if (e < E) {
            s[it] = ei[e];
            t[it] = ei[E + e];
            atomicAdd(&hist[t[it] >> 8], 1);
        } else {
            s[it] = -1;
        }
    }
    __syncthreads();
    // reserve contiguous global range per (block,bucket); hist becomes cursor
    for (int i = tid; i < nbuck; i += 256) {
        int c = hist[i];
        hist[i] = c ? atomicAdd(&bcur[i], c) : 0;
    }
    __syncthreads();
#pragma unroll
    for (int it = 0; it < 16; ++it) {
        if (s[it] >= 0) {
            int b = t[it] >> 8;
            int p = atomicAdd(&hist[b], 1);
            binned[p] = ((unsigned)s[it] << 8) | (unsigned)(t[it] & 255);
        }
    }
}

// phase B: per-bucket LDS counting sort -> per-node CSR (adj, rowptr off, dinv)
__global__ void bucket_sort(const int* __restrict__ boff, const unsigned* __restrict__ binned,
                            int* __restrict__ off, int* __restrict__ adj,
                            float* __restrict__ dinv, int N, int E) {
    __shared__ int lcur[NPB];
    __shared__ int sh[NPB];
    int bid = blockIdx.x, tid = threadIdx.x;  // 256 threads
    int node0 = bid << 8;
    int e0 = boff[bid], e1 = boff[bid + 1];
    lcur[tid] = 0;
    __syncthreads();
    for (int e = e0 + tid; e < e1; e += 256)
        atomicAdd(&lcur[binned[e] & 255], 1);
    __syncthreads();
    int v = lcur[tid];
    sh[tid] = v;
    __syncthreads();
    for (int d = 1; d < NPB; d <<= 1) {
        int t = (tid >= d) ? sh[tid - d] : 0;
        __syncthreads();
        sh[tid] += t;
        __syncthreads();
    }
    int excl = sh[tid] - v;
    __syncthreads();
    lcur[tid] = excl;
    int node = node0 + tid;
    if (node < N) {
        off[node] = e0 + excl;
        dinv[node] = rsqrtf((float)v + 1.0f);
    }
    if (tid == 0 && bid == gridDim.x - 1) off[N] = E;
    __syncthreads();
    for (int e = e0 + tid; e < e1; e += 256) {
        unsigned u = binned[e];
        int p = atomicAdd(&lcur[u & 255], 1);
        adj[e0 + p] = (int)(u >> 8);
    }
}

// one wave per node: acc = h[n]*dinv[n] + sum_s h[s]*dinv[s]; agg = acc*dinv[n]
// out = x + relu(agg + b), all fused
__global__ void gather_agg(const int* __restrict__ off, const int* __restrict__ adj,
                           const float* __restrict__ h, const float* __restrict__ dinv,
                           const float* __restrict__ x, const float* __restrict__ b,
                           float* __restrict__ out, int N) {
    int node = blockIdx.x * 4 + (threadIdx.x >> 6);
    int lane = threadIdx.x & 63;
    if (node >= N) return;
    int start = off[node];
    int m = off[node + 1] - start;
    float dn = dinv[node];
    float acc = h[(long)node * DIM + lane] * dn;  // self loop (x dn at end -> dn^2)
    for (int c = 0; c < m; c += 64) {
        int rem = m - c;
        int take = rem < 64 ? rem : 64;
        int s = (lane < take) ? adj[start + c + lane] : 0;
        float w = (lane < take) ? dinv[s] : 0.f;
        for (int i = 0; i < take; ++i) {
            int si = __shfl(s, i);
            float wi = __shfl(w, i);
            acc += h[(long)si * DIM + lane] * wi;
        }
    }
    float val = acc * dn + b[lane];
    long gi = (long)node * DIM + lane;
    out[gi] = x[gi] + fmaxf(val, 0.f);
}

extern "C" void kernel_launch(void* const* d_in, const int* in_sizes, int n_in,
                              void* d_out, int out_size, void* d_ws, size_t ws_size,
                              hipStream_t stream) {
    const float* x = (const float*)d_in[0];
    const int* ei  = (const int*)d_in[1];
    const float* W = (const float*)d_in[2];
    const float* b = (const float*)d_in[3];
    float* out = (float*)d_out;

    int N = in_sizes[0] / DIM;
    int E = in_sizes[1] / 2;
    int nbuck = (N + NPB - 1) / NPB;  // 391

    char* ws = (char*)d_ws;
    size_t o = 0;
    float* h     = (float*)(ws + o); o += (size_t)N * DIM * sizeof(float);
    float* dinv  = (float*)(ws + o); o += (size_t)N * sizeof(float);
    int*   off   = (int*)(ws + o);   o += (size_t)(N + 1) * sizeof(int);
    int*   bcount= (int*)(ws + o);   o += (size_t)nbuck * sizeof(int);
    int*   boff  = (int*)(ws + o);   o += (size_t)(nbuck + 1) * sizeof(int);
    int*   bcur  = (int*)(ws + o);   o += (size_t)nbuck * sizeof(int);
    unsigned* binned = (unsigned*)(ws + o); o += (size_t)E * sizeof(unsigned);
    int*   adj   = (int*)(ws + o);   o += (size_t)E * sizeof(int);

    gcn_matmul<<<(N + 3) / 4, 256, 0, stream>>>(x, W, h, N);
    zero_i32<<<(nbuck + 255) / 256, 256, 0, stream>>>(bcount, nbuck);
    count_buckets<<<512, 256, 0, stream>>>(ei, bcount, E, nbuck);
    scan_buckets<<<1, MAXBUCK, 0, stream>>>(bcount, boff, bcur, nbuck, E);
    bin_edges<<<(E + CHUNK - 1) / CHUNK, 256, 0, stream>>>(ei, bcur, binned, E, nbuck);
    bucket_sort<<<nbuck, 256, 0, stream>>>(boff, binned, off, adj, dinv, N, E);
    gather_agg<<<(N + 3) / 4, 256, 0, stream>>>(off, adj, h, dinv, x, b, out, N);
}

// Round 10
// 184.018 us; speedup vs baseline: 5.0543x; 1.2128x over previous
//
#include <hip/hip_runtime.h>

#define DIM 64
#define NPB 256          // nodes per bucket (bucket id = dst >> 8)
#define MAXBUCK 512      // N up to 131072
#define CHUNK 4096       // edges per binning block

// h = x @ W   (x: [N,64], W: [64,64])
__global__ void gcn_matmul(const float* __restrict__ x, const float* __restrict__ W,
                           float* __restrict__ h, int N) {
    __shared__ float Wl[DIM][DIM];
    __shared__ float xs[4][DIM];
    int tid = threadIdx.x;
    for (int i = tid; i < DIM * DIM; i += 256) Wl[i / DIM][i % DIM] = W[i];
    int node0 = blockIdx.x * 4;
    int gidx = node0 * DIM + tid;
    xs[tid / DIM][tid % DIM] = (gidx < N * DIM) ? x[gidx] : 0.f;
    __syncthreads();
    int nl = tid / DIM, d = tid % DIM;
    int node = node0 + nl;
    if (node < N) {
        float acc = 0.f;
#pragma unroll
        for (int k = 0; k < DIM; ++k) acc += xs[nl][k] * Wl[k][d];
        h[node * DIM + d] = acc;
    }
}

__global__ void zero_i32(int* __restrict__ p, int n) {
    int i = blockIdx.x * 256 + threadIdx.x;
    if (i < n) p[i] = 0;
}

// bucket histogram only (LDS-aggregated, no per-node atomics)
__global__ void count_buckets(const int* __restrict__ ei, int* __restrict__ bcount,
                              int E, int nbuck) {
    __shared__ int hist[MAXBUCK];
    int tid = threadIdx.x;
    for (int i = tid; i < nbuck; i += 256) hist[i] = 0;
    __syncthreads();
    for (long e = (long)blockIdx.x * 256 + tid; e < E; e += (long)gridDim.x * 256)
        atomicAdd(&hist[ei[E + e] >> 8], 1);
    __syncthreads();
    for (int i = tid; i < nbuck; i += 256)
        if (hist[i]) atomicAdd(&bcount[i], hist[i]);
}

// single-block exclusive scan of bucket counts -> boff, init bcur
__global__ void scan_buckets(const int* __restrict__ bcount, int* __restrict__ boff,
                             int* __restrict__ bcur, int nbuck, int E) {
    __shared__ int sh[MAXBUCK];
    int tid = threadIdx.x;  // 512
    int v = (tid < nbuck) ? bcount[tid] : 0;
    sh[tid] = v;
    __syncthreads();
    for (int d = 1; d < MAXBUCK; d <<= 1) {
        int t = (tid >= d) ? sh[tid - d] : 0;
        __syncthreads();
        sh[tid] += t;
        __syncthreads();
    }
    if (tid < nbuck) {
        int o = sh[tid] - v;
        boff[tid] = o;
        bcur[tid] = o;
    }
    if (tid == 0) boff[nbuck] = E;
}

// phase A: bin edges into bucket-contiguous storage; entry = (src<<8) | (dst&255)
__global__ void bin_edges(const int* __restrict__ ei, int* __restrict__ bcur,
                          unsigned* __restrict__ binned, int E, int nbuck) {
    __shared__ int hist[MAXBUCK];
    int tid = threadIdx.x;
    long e0 = (long)blockIdx.x * CHUNK;
    for (int i = tid; i < nbuck; i += 256) hist[i] = 0;
    __syncthreads();
    int s[16], t[16];
#pragma unroll
    for (int it = 0; it < 16; ++it) {
        long e = e0 + it * 256 + tid;
        if (e < E) {
            s[it] = ei[e];
            t[it] = ei[E + e];
            atomicAdd(&hist[t[it] >> 8], 1);
        } else {
            s[it] = -1;
        }
    }
    __syncthreads();
    // reserve contiguous global range per (block,bucket); hist becomes cursor
    for (int i = tid; i < nbuck; i += 256) {
        int c = hist[i];
        hist[i] = c ? atomicAdd(&bcur[i], c) : 0;
    }
    __syncthreads();
#pragma unroll
    for (int it = 0; it < 16; ++it) {
        if (s[it] >= 0) {
            int b = t[it] >> 8;
            int p = atomicAdd(&hist[b], 1);
            binned[p] = ((unsigned)s[it] << 8) | (unsigned)(t[it] & 255);
        }
    }
}

// phase B: per-bucket LDS counting sort -> per-node CSR (adj, rowptr off, dinv)
__global__ void bucket_sort(const int* __restrict__ boff, const unsigned* __restrict__ binned,
                            int* __restrict__ off, int* __restrict__ adj,
                            float* __restrict__ dinv, int N, int E) {
    __shared__ int lcur[NPB];
    __shared__ int sh[NPB];
    int bid = blockIdx.x, tid = threadIdx.x;  // 256 threads
    int node0 = bid << 8;
    int e0 = boff[bid], e1 = boff[bid + 1];
    lcur[tid] = 0;
    __syncthreads();
    for (int e = e0 + tid; e < e1; e += 256)
        atomicAdd(&lcur[binned[e] & 255], 1);
    __syncthreads();
    int v = lcur[tid];
    sh[tid] = v;
    __syncthreads();
    for (int d = 1; d < NPB; d <<= 1) {
        int t = (tid >= d) ? sh[tid - d] : 0;
        __syncthreads();
        sh[tid] += t;
        __syncthreads();
    }
    int excl = sh[tid] - v;
    __syncthreads();
    lcur[tid] = excl;
    int node = node0 + tid;
    if (node < N) {
        off[node] = e0 + excl;
        dinv[node] = rsqrtf((float)v + 1.0f);
    }
    if (tid == 0 && bid == gridDim.x - 1) off[N] = E;
    __syncthreads();
    for (int e = e0 + tid; e < e1; e += 256) {
        unsigned u = binned[e];
        int p = atomicAdd(&lcur[u & 255], 1);
        adj[e0 + p] = (int)(u >> 8);
    }
}

// one wave per node, 8-way software-pipelined gather:
// acc = h[n]*dinv[n] + sum_s h[s]*dinv[s]; out = x + relu(acc*dinv[n] + b)
__global__ void gather_agg(const int* __restrict__ off, const int* __restrict__ adj,
                           const float* __restrict__ h, const float* __restrict__ dinv,
                           const float* __restrict__ x, const float* __restrict__ b,
                           float* __restrict__ out, int N) {
    int node = blockIdx.x * 4 + (threadIdx.x >> 6);
    int lane = threadIdx.x & 63;
    if (node >= N) return;
    int start = off[node];
    int m = off[node + 1] - start;
    float dn = dinv[node];
    float acc = h[(long)node * DIM + lane] * dn;  // self loop (x dn at end -> dn^2)
    for (int c = 0; c < m; c += 64) {
        int rem = m - c;
        int take = rem < 64 ? rem : 64;
        int s = (lane < take) ? adj[start + c + lane] : 0;
        float w = (lane < take) ? dinv[s] : 0.f;
        int i = 0;
        // 8 independent loads in flight per batch -> 8x MLP
        for (; i + 8 <= take; i += 8) {
            int s0 = __shfl(s, i + 0), s1 = __shfl(s, i + 1);
            int s2 = __shfl(s, i + 2), s3 = __shfl(s, i + 3);
            int s4 = __shfl(s, i + 4), s5 = __shfl(s, i + 5);
            int s6 = __shfl(s, i + 6), s7 = __shfl(s, i + 7);
            float w0 = __shfl(w, i + 0), w1 = __shfl(w, i + 1);
            float w2 = __shfl(w, i + 2), w3 = __shfl(w, i + 3);
            float w4 = __shfl(w, i + 4), w5 = __shfl(w, i + 5);
            float w6 = __shfl(w, i + 6), w7 = __shfl(w, i + 7);
            float v0 = h[(long)s0 * DIM + lane];
            float v1 = h[(long)s1 * DIM + lane];
            float v2 = h[(long)s2 * DIM + lane];
            float v3 = h[(long)s3 * DIM + lane];
            float v4 = h[(long)s4 * DIM + lane];
            float v5 = h[(long)s5 * DIM + lane];
            float v6 = h[(long)s6 * DIM + lane];
            float v7 = h[(long)s7 * DIM + lane];
            acc += v0 * w0; acc += v1 * w1; acc += v2 * w2; acc += v3 * w3;
            acc += v4 * w4; acc += v5 * w5; acc += v6 * w6; acc += v7 * w7;
        }
        for (; i < take; ++i) {
            int si = __shfl(s, i);
            float wi = __shfl(w, i);
            acc += h[(long)si * DIM + lane] * wi;
        }
    }
    float val = acc * dn + b[lane];
    long gi = (long)node * DIM + lane;
    out[gi] = x[gi] + fmaxf(val, 0.f);
}

extern "C" void kernel_launch(void* const* d_in, const int* in_sizes, int n_in,
                              void* d_out, int out_size, void* d_ws, size_t ws_size,
                              hipStream_t stream) {
    const float* x = (const float*)d_in[0];
    const int* ei  = (const int*)d_in[1];
    const float* W = (const float*)d_in[2];
    const float* b = (const float*)d_in[3];
    float* out = (float*)d_out;

    int N = in_sizes[0] / DIM;
    int E = in_sizes[1] / 2;
    int nbuck = (N + NPB - 1) / NPB;  // 391

    char* ws = (char*)d_ws;
    size_t o = 0;
    float* h     = (float*)(ws + o); o += (size_t)N * DIM * sizeof(float);
    float* dinv  = (float*)(ws + o); o += (size_t)N * sizeof(float);
    int*   off   = (int*)(ws + o);   o += (size_t)(N + 1) * sizeof(int);
    int*   bcount= (int*)(ws + o);   o += (size_t)nbuck * sizeof(int);
    int*   boff  = (int*)(ws + o);   o += (size_t)(nbuck + 1) * sizeof(int);
    int*   bcur  = (int*)(ws + o);   o += (size_t)nbuck * sizeof(int);
    unsigned* binned = (unsigned*)(ws + o); o += (size_t)E * sizeof(unsigned);
    int*   adj   = (int*)(ws + o);   o += (size_t)E * sizeof(int);

    gcn_matmul<<<(N + 3) / 4, 256, 0, stream>>>(x, W, h, N);
    zero_i32<<<(nbuck + 255) / 256, 256, 0, stream>>>(bcount, nbuck);
    count_buckets<<<512, 256, 0, stream>>>(ei, bcount, E, nbuck);
    scan_buckets<<<1, MAXBUCK, 0, stream>>>(bcount, boff, bcur, nbuck, E);
    bin_edges<<<(E + CHUNK - 1) / CHUNK, 256, 0, stream>>>(ei, bcur, binned, E, nbuck);
    bucket_sort<<<nbuck, 256, 0, stream>>>(boff, binned, off, adj, dinv, N, E);
    gather_agg<<<(N + 3) / 4, 256, 0, stream>>>(off, adj, h, dinv, x, b, out, N);
}

// Round 13
// 156.890 us; speedup vs baseline: 5.9282x; 1.1729x over previous
//
#include <hip/hip_runtime.h>

#define DIM 64
#define NPB 256          // nodes per bucket (bucket id = dst >> 8)
#define MAXBUCK 512      // N up to 131072
#define CHUNK 4096       // edges per binning block

__device__ __forceinline__ unsigned short f2bf(float v) {
    unsigned u = __float_as_uint(v);
    unsigned r = (u + 0x7fffu + ((u >> 16) & 1u)) >> 16;  // RNE
    return (unsigned short)r;
}

// h = x @ W   (x: [N,64], W: [64,64]) -> bf16 rows (128 B each)
__global__ void gcn_matmul(const float* __restrict__ x, const float* __restrict__ W,
                           unsigned short* __restrict__ hbf, int N) {
    __shared__ float Wl[DIM][DIM];
    __shared__ float xs[4][DIM];
    int tid = threadIdx.x;
    for (int i = tid; i < DIM * DIM; i += 256) Wl[i / DIM][i % DIM] = W[i];
    int node0 = blockIdx.x * 4;
    int gidx = node0 * DIM + tid;
    xs[tid / DIM][tid % DIM] = (gidx < N * DIM) ? x[gidx] : 0.f;
    __syncthreads();
    int nl = tid / DIM, d = tid % DIM;
    int node = node0 + nl;
    if (node < N) {
        float acc = 0.f;
#pragma unroll
        for (int k = 0; k < DIM; ++k) acc += xs[nl][k] * Wl[k][d];
        hbf[(long)node * DIM + d] = f2bf(acc);
    }
}

__global__ void zero_i32(int* __restrict__ p, int n) {
    int i = blockIdx.x * 256 + threadIdx.x;
    if (i < n) p[i] = 0;
}

// bucket histogram only (LDS-aggregated)
__global__ void count_buckets(const int* __restrict__ ei, int* __restrict__ bcount,
                              int E, int nbuck) {
    __shared__ int hist[MAXBUCK];
    int tid = threadIdx.x;
    for (int i = tid; i < nbuck; i += 256) hist[i] = 0;
    __syncthreads();
    for (long e = (long)blockIdx.x * 256 + tid; e < E; e += (long)gridDim.x * 256)
        atomicAdd(&hist[ei[E + e] >> 8], 1);
    __syncthreads();
    for (int i = tid; i < nbuck; i += 256)
        if (hist[i]) atomicAdd(&bcount[i], hist[i]);
}

// single-block exclusive scan of bucket counts -> boff, init bcur
__global__ void scan_buckets(const int* __restrict__ bcount, int* __restrict__ boff,
                             int* __restrict__ bcur, int nbuck, int E) {
    __shared__ int sh[MAXBUCK];
    int tid = threadIdx.x;  // 512
    int v = (tid < nbuck) ? bcount[tid] : 0;
    sh[tid] = v;
    __syncthreads();
    for (int d = 1; d < MAXBUCK; d <<= 1) {
        int t = (tid >= d) ? sh[tid - d] : 0;
        __syncthreads();
        sh[tid] += t;
        __syncthreads();
    }
    if (tid < nbuck) {
        int o = sh[tid] - v;
        boff[tid] = o;
        bcur[tid] = o;
    }
    if (tid == 0) boff[nbuck] = E;
}

// phase A: bin edges into bucket-contiguous storage; entry = (src<<8) | (dst&255)
__global__ void bin_edges(const int* __restrict__ ei, int* __restrict__ bcur,
                          unsigned* __restrict__ binned, int E, int nbuck) {
    __shared__ int hist[MAXBUCK];
    int tid = threadIdx.x;
    long e0 = (long)blockIdx.x * CHUNK;
    for (int i = tid; i < nbuck; i += 256) hist[i] = 0;
    __syncthreads();
    int s[16], t[16];
#pragma unroll
    for (int it = 0; it < 16; ++it) {
        long e = e0 + it * 256 + tid;
        if (e < E) {
            s[it] = ei[e];
            t[it] = ei[E + e];
            atomicAdd(&hist[t[it] >> 8], 1);
        } else {
            s[it] = -1;
        }
    }
    __syncthreads();
    for (int i = tid; i < nbuck; i += 256) {
        int c = hist[i];
        hist[i] = c ? atomicAdd(&bcur[i], c) : 0;
    }
    __syncthreads();
#pragma unroll
    for (int it = 0; it < 16; ++it) {
        if (s[it] >= 0) {
            int b = t[it] >> 8;
            int p = atomicAdd(&hist[b], 1);
            binned[p] = ((unsigned)s[it] << 8) | (unsigned)(t[it] & 255);
        }
    }
}

// phase B: per-bucket LDS counting sort -> per-node CSR (adj, rowptr off, dinv)
__global__ void bucket_sort(const int* __restrict__ boff, const unsigned* __restrict__ binned,
                            int* __restrict__ off, int* __restrict__ adj,
                            float* __restrict__ dinv, int N, int E) {
    __shared__ int lcur[NPB];
    __shared__ int sh[NPB];
    int bid = blockIdx.x, tid = threadIdx.x;  // 256 threads
    int node0 = bid << 8;
    int e0 = boff[bid], e1 = boff[bid + 1];
    lcur[tid] = 0;
    __syncthreads();
    for (int e = e0 + tid; e < e1; e += 256)
        atomicAdd(&lcur[binned[e] & 255], 1);
    __syncthreads();
    int v = lcur[tid];
    sh[tid] = v;
    __syncthreads();
    for (int d = 1; d < NPB; d <<= 1) {
        int t = (tid >= d) ? sh[tid - d] : 0;
        __syncthreads();
        sh[tid] += t;
        __syncthreads();
    }
    int excl = sh[tid] - v;
    __syncthreads();
    lcur[tid] = excl;
    int node = node0 + tid;
    if (node < N) {
        off[node] = e0 + excl;
        dinv[node] = rsqrtf((float)v + 1.0f);
    }
    if (tid == 0 && bid == gridDim.x - 1) off[N] = E;
    __syncthreads();
    for (int e = e0 + tid; e < e1; e += 256) {
        unsigned u = binned[e];
        int p = atomicAdd(&lcur[u & 255], 1);
        adj[e0 + p] = (int)(u >> 8);
    }
}

// one wave per node; 2 edges per load instruction (bf16 rows), 8 loads in flight.
// lane = (sub = lane>>5 selects edge-of-pair, f = lane&31 selects feature pair)
__global__ void gather_agg(const int* __restrict__ off, const int* __restrict__ adj,
                           const unsigned* __restrict__ hb, const float* __restrict__ dinv,
                           const float2* __restrict__ x2, const float2* __restrict__ b2,
                           float2* __restrict__ o2, int N) {
    int node = blockIdx.x * 4 + (threadIdx.x >> 6);
    int lane = threadIdx.x & 63;
    if (node >= N) return;
    int sub = lane >> 5;     // which edge of the pair
    int f = lane & 31;       // feature-pair index (features 2f, 2f+1)
    int start = off[node];
    int m = off[node + 1] - start;
    float dn = dinv[node];
    float2 acc; acc.x = 0.f; acc.y = 0.f;

    for (int c = 0; c < m; c += 64) {
        int rem = m - c;
        int take = rem < 64 ? rem : 64;
        int s = (lane < take) ? adj[start + c + lane] : 0;
        float w = (lane < take) ? dinv[s] : 0.f;
        for (int i = 0; i < take; i += 16) {
            int i0 = i + 0 + sub,  i1 = i + 2 + sub,  i2 = i + 4 + sub,  i3 = i + 6 + sub;
            int i4 = i + 8 + sub,  i5 = i + 10 + sub, i6 = i + 12 + sub, i7 = i + 14 + sub;
            int t0 = __shfl(s, i0), t1 = __shfl(s, i1), t2 = __shfl(s, i2), t3 = __shfl(s, i3);
            int t4 = __shfl(s, i4), t5 = __shfl(s, i5), t6 = __shfl(s, i6), t7 = __shfl(s, i7);
            float q0 = __shfl(w, i0), q1 = __shfl(w, i1), q2 = __shfl(w, i2), q3 = __shfl(w, i3);
            float q4 = __shfl(w, i4), q5 = __shfl(w, i5), q6 = __shfl(w, i6), q7 = __shfl(w, i7);
            unsigned u0 = hb[(long)t0 * 32 + f];
            unsigned u1 = hb[(long)t1 * 32 + f];
            unsigned u2 = hb[(long)t2 * 32 + f];
            unsigned u3 = hb[(long)t3 * 32 + f];
            unsigned u4 = hb[(long)t4 * 32 + f];
            unsigned u5 = hb[(long)t5 * 32 + f];
            unsigned u6 = hb[(long)t6 * 32 + f];
            unsigned u7 = hb[(long)t7 * 32 + f];
            acc.x += __uint_as_float(u0 << 16) * q0;
            acc.y += __uint_as_float(u0 & 0xffff0000u) * q0;
            acc.x += __uint_as_float(u1 << 16) * q1;
            acc.y += __uint_as_float(u1 & 0xffff0000u) * q1;
            acc.x += __uint_as_float(u2 << 16) * q2;
            acc.y += __uint_as_float(u2 & 0xffff0000u) * q2;
            acc.x += __uint_as_float(u3 << 16) * q3;
            acc.y += __uint_as_float(u3 & 0xffff0000u) * q3;
            acc.x += __uint_as_float(u4 << 16) * q4;
            acc.y += __uint_as_float(u4 & 0xffff0000u) * q4;
            acc.x += __uint_as_float(u5 << 16) * q5;
            acc.y += __uint_as_float(u5 & 0xffff0000u) * q5;
            acc.x += __uint_as_float(u6 << 16) * q6;
            acc.y += __uint_as_float(u6 & 0xffff0000u) * q6;
            acc.x += __uint_as_float(u7 << 16) * q7;
            acc.y += __uint_as_float(u7 & 0xffff0000u) * q7;
        }
    }
    // merge the two half-wave edge sums (lane <-> lane^32)
    acc.x += __shfl_xor(acc.x, 32);
    acc.y += __shfl_xor(acc.y, 32);
    // self loop (post-merge, once)
    unsigned us = hb[(long)node * 32 + f];
    acc.x += __uint_as_float(us << 16) * dn;
    acc.y += __uint_as_float(us & 0xffff0000u) * dn;

    if (lane < 32) {
        long gi = (long)node * 32 + f;
        float2 bb = b2[f];
        float2 xx = x2[gi];
        float2 r;
        float vx = acc.x * dn + bb.x;
        float vy = acc.y * dn + bb.y;
        r.x = xx.x + fmaxf(vx, 0.f);
        r.y = xx.y + fmaxf(vy, 0.f);
        o2[gi] = r;
    }
}

extern "C" void kernel_launch(void* const* d_in, const int* in_sizes, int n_in,
                              void* d_out, int out_size, void* d_ws, size_t ws_size,
                              hipStream_t stream) {
    const float* x = (const float*)d_in[0];
    const int* ei  = (const int*)d_in[1];
    const float* W = (const float*)d_in[2];
    const float* b = (const float*)d_in[3];
    float* out = (float*)d_out;

    int N = in_sizes[0] / DIM;
    int E = in_sizes[1] / 2;
    int nbuck = (N + NPB - 1) / NPB;  // 391

    char* ws = (char*)d_ws;
    size_t o = 0;
    unsigned short* hbf = (unsigned short*)(ws + o); o += (size_t)N * DIM * sizeof(unsigned short);
    float* dinv  = (float*)(ws + o); o += (size_t)N * sizeof(float);
    int*   off   = (int*)(ws + o);   o += (size_t)(N + 1) * sizeof(int);
    int*   bcount= (int*)(ws + o);   o += (size_t)nbuck * sizeof(int);
    int*   boff  = (int*)(ws + o);   o += (size_t)(nbuck + 1) * sizeof(int);
    int*   bcur  = (int*)(ws + o);   o += (size_t)nbuck * sizeof(int);
    unsigned* binned = (unsigned*)(ws + o); o += (size_t)E * sizeof(unsigned);
    int*   adj   = (int*)(ws + o);   o += (size_t)E * sizeof(int);

    gcn_matmul<<<(N + 3) / 4, 256, 0, stream>>>(x, W, hbf, N);
    zero_i32<<<(nbuck + 255) / 256, 256, 0, stream>>>(bcount, nbuck);
    count_buckets<<<512, 256, 0, stream>>>(ei, bcount, E, nbuck);
    scan_buckets<<<1, MAXBUCK, 0, stream>>>(bcount, boff, bcur, nbuck, E);
    bin_edges<<<(E + CHUNK - 1) / CHUNK, 256, 0, stream>>>(ei, bcur, binned, E, nbuck);
    bucket_sort<<<nbuck, 256, 0, stream>>>(boff, binned, off, adj, dinv, N, E);
    gather_agg<<<(N + 3) / 4, 256, 0, stream>>>(off, adj, (const unsigned*)hbf, dinv,
                                                (const float2*)x, (const float2*)b,
                                                (float2*)out, N);
}